// Round 1
// baseline (514.322 us; speedup 1.0000x reference)
//
#include <hip/hip_runtime.h>

#define Cc  256
#define Hh  96
#define Ww  96
#define HW  (Hh*Ww)          // 9216
#define OC  32
#define HS  192
#define WS_ 192
#define Bb  8

// Kernel 1: 1x1 conv (C=256 -> 32) + pixel_shuffle(2) + tanh + grid build.
// One thread per input pixel. Stores clamped absolute source coords (gx,gy)
// into grid_buf[bg][hs][ws][2], bg = b*4 + group.
__global__ __launch_bounds__(128) void conv_offset_kernel(
    const float* __restrict__ x, const float* __restrict__ w,
    const float* __restrict__ bias, float* __restrict__ grid_buf)
{
    __shared__ float wt[Cc * OC];  // wt[c*32 + o]  (transposed), 32 KB
    const int tid = threadIdx.x;
    // conflict-free LDS writes (consecutive threads -> consecutive addresses);
    // global reads are scattered but it's a one-time 32 KB read (L2-resident).
    for (int l = tid; l < Cc * OC; l += 128) {
        int cc = l >> 5, oo = l & 31;
        wt[l] = w[oo * Cc + cc];
    }
    __syncthreads();

    const int p  = blockIdx.x * 128 + tid;   // 73728 pixels exactly
    const int b  = p / HW;
    const int hw = p - b * HW;
    const float* xp = x + (size_t)b * Cc * HW + hw;

    float acc[OC];
    #pragma unroll
    for (int o = 0; o < OC; ++o) acc[o] = bias[o];

    #pragma unroll 4
    for (int c = 0; c < Cc; ++c) {
        float xv = xp[(size_t)c * HW];          // coalesced across lanes
        const float* wr = &wt[c * OC];          // broadcast (same addr all lanes)
        #pragma unroll
        for (int o = 0; o < OC; ++o) acc[o] = fmaf(wr[o], xv, acc[o]);
    }

    const int h = hw / Ww, ww = hw - (hw / Ww) * Ww;
    // o = co*4 + i*2 + j ; co = gr*2 + k (k: 0 = x-coord, 1 = y-coord)
    #pragma unroll
    for (int o = 0; o < OC; ++o) {
        int co  = o >> 2;
        int rem = o & 3;
        int i   = rem >> 1;
        int j   = rem & 1;
        int gr  = co >> 1;
        int k   = co & 1;
        int hs  = 2 * h + i;
        int ws  = 2 * ww + j;
        float t = tanhf(acc[o]);
        // unnormalized coord: (grid_norm + 1)*48 - 0.5, grid_norm = (2s+1)/192 - 1 + 0.125*t
        float coord = (k == 0) ? (0.5f * (float)ws - 0.25f + 6.0f * t)
                               : (0.5f * (float)hs - 0.25f + 6.0f * t);
        coord = fminf(fmaxf(coord, 0.0f), 95.0f);   // border clamp
        int bg = b * 4 + gr;
        grid_buf[(((size_t)bg * HS + hs) * WS_ + ws) * 2 + k] = coord;
    }
}

// Kernel 2: bilinear gather. One thread per 4 consecutive output ws.
__global__ __launch_bounds__(256) void sample_kernel(
    const float* __restrict__ x, const float* __restrict__ grid_buf,
    float* __restrict__ out)
{
    const int t = blockIdx.x * 256 + threadIdx.x;   // < 18,874,368
    int ws4 = t % 48;
    int r   = t / 48;
    int hs  = r % HS;  r /= HS;
    int c   = r & 255;
    int b   = r >> 8;
    int bg  = b * 4 + (c >> 6);

    const float* plane = x + ((size_t)b * Cc + c) * HW;   // 96x96 source plane
    const float4* gp = (const float4*)(grid_buf +
                        (((size_t)bg * HS + hs) * WS_ + ws4 * 4) * 2);
    float4 g01 = gp[0];   // gx0,gy0,gx1,gy1
    float4 g23 = gp[1];   // gx2,gy2,gx3,gy3
    float gx[4] = {g01.x, g01.z, g23.x, g23.z};
    float gy[4] = {g01.y, g01.w, g23.y, g23.w};

    float res[4];
    #pragma unroll
    for (int q = 0; q < 4; ++q) {
        float fx = gx[q], fy = gy[q];
        float x0f = floorf(fx), y0f = floorf(fy);
        float wx = fx - x0f,  wy = fy - y0f;
        int x0 = (int)x0f, y0 = (int)y0f;
        int x1 = min(x0 + 1, Ww - 1);
        int y1 = min(y0 + 1, Hh - 1);
        const float* row0 = plane + y0 * Ww;
        const float* row1 = plane + y1 * Ww;
        float v00 = row0[x0], v01 = row0[x1];
        float v10 = row1[x0], v11 = row1[x1];
        float top = v00 + (v01 - v00) * wx;
        float bot = v10 + (v11 - v10) * wx;
        res[q] = top + (bot - top) * wy;
    }
    float4* op = (float4*)(out + (size_t)t * 4);
    *op = make_float4(res[0], res[1], res[2], res[3]);
}

extern "C" void kernel_launch(void* const* d_in, const int* in_sizes, int n_in,
                              void* d_out, int out_size, void* d_ws, size_t ws_size,
                              hipStream_t stream) {
    const float* x    = (const float*)d_in[0];
    const float* w    = (const float*)d_in[1];
    const float* bias = (const float*)d_in[2];
    float* out        = (float*)d_out;
    float* grid_buf   = (float*)d_ws;   // 32*192*192*2 floats = 9.4 MB

    // 73728 pixels / 128 = 576 blocks (exact)
    conv_offset_kernel<<<576, 128, 0, stream>>>(x, w, bias, grid_buf);
    // 75,497,472 outputs / 4 per thread / 256 = 73728 blocks (exact)
    sample_kernel<<<73728, 256, 0, stream>>>(x, grid_buf, out);
}

// Round 2
// 485.879 us; speedup vs baseline: 1.0585x; 1.0585x over previous
//
#include <hip/hip_runtime.h>

#define Cc  256
#define Hh  96
#define Ww  96
#define HW  (Hh*Ww)          // 9216
#define OC  32
#define HS  192
#define WSS 192
#define PLANE (HS*WSS)       // 36864

// Kernel 1: 1x1 conv (C=256 -> 32) + pixel_shuffle(2) + tanh + grid build.
// One thread per input pixel. Stores clamped absolute source coords (gx,gy)
// into grid_buf[bg][hs][ws][2], bg = b*4 + group.
__global__ __launch_bounds__(128) void conv_offset_kernel(
    const float* __restrict__ x, const float* __restrict__ w,
    const float* __restrict__ bias, float* __restrict__ grid_buf)
{
    __shared__ float wt[Cc * OC];  // wt[c*32 + o]  (transposed), 32 KB
    const int tid = threadIdx.x;
    for (int l = tid; l < Cc * OC; l += 128) {
        int cc = l >> 5, oo = l & 31;
        wt[l] = w[oo * Cc + cc];
    }
    __syncthreads();

    const int p  = blockIdx.x * 128 + tid;   // 73728 pixels exactly
    const int b  = p / HW;
    const int hw = p - b * HW;
    const float* xp = x + (size_t)b * Cc * HW + hw;

    float acc[OC];
    #pragma unroll
    for (int o = 0; o < OC; ++o) acc[o] = bias[o];

    // ds_read_b128 broadcast reads of weights: 8 LDS instrs per channel (was 32)
    #pragma unroll 2
    for (int c = 0; c < Cc; ++c) {
        float xv = xp[(size_t)c * HW];                 // coalesced across lanes
        const float4* wr4 = (const float4*)&wt[c * OC]; // 16B-aligned broadcast
        #pragma unroll
        for (int o4 = 0; o4 < 8; ++o4) {
            float4 wv = wr4[o4];
            acc[4*o4+0] = fmaf(wv.x, xv, acc[4*o4+0]);
            acc[4*o4+1] = fmaf(wv.y, xv, acc[4*o4+1]);
            acc[4*o4+2] = fmaf(wv.z, xv, acc[4*o4+2]);
            acc[4*o4+3] = fmaf(wv.w, xv, acc[4*o4+3]);
        }
    }

    const int h = hw / Ww, ww = hw - (hw / Ww) * Ww;
    // o = co*4 + i*2 + j ; co = gr*2 + k (k: 0 = x-coord, 1 = y-coord)
    #pragma unroll
    for (int o = 0; o < OC; ++o) {
        int co  = o >> 2;
        int rem = o & 3;
        int i   = rem >> 1;
        int j   = rem & 1;
        int gr  = co >> 1;
        int k   = co & 1;
        int hs  = 2 * h + i;
        int ws  = 2 * ww + j;
        float t = tanhf(acc[o]);
        // absolute source coord: (grid_norm + 1)*48 - 0.5
        float coord = (k == 0) ? (0.5f * (float)ws - 0.25f + 6.0f * t)
                               : (0.5f * (float)hs - 0.25f + 6.0f * t);
        coord = fminf(fmaxf(coord, 0.0f), 95.0f);   // border clamp
        int bg = b * 4 + gr;
        grid_buf[(((size_t)bg * HS + hs) * WSS + ws) * 2 + k] = coord;
    }
}

// Kernel 2: bilinear gather with the full source plane staged in LDS.
// One block per (b,c) plane; 256 threads x 144 outputs each.
__global__ __launch_bounds__(256) void sample_kernel(
    const float* __restrict__ x, const float* __restrict__ grid_buf,
    float* __restrict__ out)
{
    __shared__ float pl[9344];           // 9216 plane + 128 pad (border taps ×0)
    const int bc  = blockIdx.x;          // b*256 + c
    const int b   = bc >> 8;
    const int c   = bc & 255;
    const int bg  = b * 4 + (c >> 6);
    const int tid = threadIdx.x;

    // stage plane: 2304 float4, coalesced, x read exactly once from HBM total
    const float4* xp4 = (const float4*)(x + (size_t)bc * HW);
    float4* pl4 = (float4*)pl;
    #pragma unroll
    for (int i = 0; i < 9; ++i) pl4[tid + 256 * i] = xp4[tid + 256 * i];
    if (tid < 128) pl[9216 + tid] = 0.0f;   // pad: out-of-range taps read 0 (weight 0)
    __syncthreads();

    const float* gbase = grid_buf + (size_t)bg * PLANE * 2;
    float* obase = out + (size_t)bc * PLANE;

    for (int r = 0; r < 36; ++r) {
        const int idx = r * 1024 + tid * 4;        // linear output idx in plane, %4==0
        const float4* gp = (const float4*)(gbase + (size_t)idx * 2); // 32B aligned
        float4 g01 = gp[0];   // gx0,gy0,gx1,gy1
        float4 g23 = gp[1];   // gx2,gy2,gx3,gy3
        float gx[4] = {g01.x, g01.z, g23.x, g23.z};
        float gy[4] = {g01.y, g01.w, g23.y, g23.w};
        float res[4];
        #pragma unroll
        for (int q = 0; q < 4; ++q) {
            float fx = gx[q], fy = gy[q];
            float x0f = floorf(fx), y0f = floorf(fy);
            float wx = fx - x0f, wy = fy - y0f;
            int base = (int)fmaf(y0f, 96.0f, x0f);  // exact int in fp32 range
            float a0 = pl[base],      a1 = pl[base + 1];   // ds_read2_b32
            float b0 = pl[base + 96], b1 = pl[base + 97];  // ds_read2_b32
            float top = a0 + (a1 - a0) * wx;
            float bot = b0 + (b1 - b0) * wx;
            res[q] = top + (bot - top) * wy;
        }
        *(float4*)(obase + idx) = make_float4(res[0], res[1], res[2], res[3]);
    }
}

extern "C" void kernel_launch(void* const* d_in, const int* in_sizes, int n_in,
                              void* d_out, int out_size, void* d_ws, size_t ws_size,
                              hipStream_t stream) {
    const float* x    = (const float*)d_in[0];
    const float* w    = (const float*)d_in[1];
    const float* bias = (const float*)d_in[2];
    float* out        = (float*)d_out;
    float* grid_buf   = (float*)d_ws;   // 32*192*192*2 floats = 9.4 MB

    conv_offset_kernel<<<576, 128, 0, stream>>>(x, w, bias, grid_buf);
    sample_kernel<<<2048, 256, 0, stream>>>(x, grid_buf, out);
}